// Round 12
// baseline (155.534 us; speedup 1.0000x reference)
//
#include <hip/hip_runtime.h>

// MHA: B=4, S=2048, D_MODEL=512, H=8, D_HEAD=64
// Wt transpose -> QKV proj GEMMs (one launch) -> flash attn -> out proj GEMM
// attn r12: r11 pipeline (phase1(t+1) || phase2(t), 1 barrier/tile) with the
// rescale-order FIX: oacc *= sc_pend BEFORE phase2(t) adds PV(t).
// (r11 bug: (oacc+PV)*sc instead of oacc*sc+PV; at t=0 sc=0 wiped PV(0).)

typedef unsigned short u16;
typedef __bf16 bf16x8 __attribute__((ext_vector_type(8)));
typedef float  f32x4  __attribute__((ext_vector_type(4)));

__device__ __forceinline__ u16 f2bf(float x) {
  unsigned u = __float_as_uint(x);
  u += 0x7fffu + ((u >> 16) & 1u);   // RNE
  return (u16)(u >> 16);
}

__device__ __forceinline__ unsigned cvtpk(float lo, float hi) {
  unsigned r;
  asm("v_cvt_pk_bf16_f32 %0, %1, %2" : "=v"(r) : "v"(lo), "v"(hi));
  return r;
}

__device__ __forceinline__ f32x4 mfma16(bf16x8 a, bf16x8 b, f32x4 c) {
  return __builtin_amdgcn_mfma_f32_16x16x32_bf16(a, b, c, 0, 0, 0);
}

__device__ __forceinline__ bf16x8 u4bf(uint4 v) {
  union { uint4 u; bf16x8 h; } c; c.u = v; return c.h;
}

// async 16B/lane global->LDS; lds dest is wave-uniform base (HW adds lane*16)
__device__ __forceinline__ void gl16(const u16* g, u16* l) {
  __builtin_amdgcn_global_load_lds(
      (const __attribute__((address_space(1))) void*)g,
      (__attribute__((address_space(3))) void*)l, 16, 0, 0);
}

#define MX3(a, b, c) fmaxf(fmaxf((a), (b)), (c))

// ---- W[k][n] fp32 -> Wt[n][k] bf16, all 4 weights in one launch ----
__global__ __launch_bounds__(256) void wtrans_k(const float* __restrict__ W0,
                                                const float* __restrict__ W1,
                                                const float* __restrict__ W2,
                                                const float* __restrict__ W3,
                                                u16* __restrict__ Wt) {
  int sel = blockIdx.y;
  const float* W = sel == 0 ? W0 : sel == 1 ? W1 : sel == 2 ? W2 : W3;
  int idx = blockIdx.x * 256 + threadIdx.x;
  int k = idx >> 9, n = idx & 511;
  Wt[sel * 262144 + n * 512 + k] = f2bf(W[idx]);
}

// ---- GEMM body: A[8192x512] @ Bt^T + bias (Bt is [n][k] bf16) ----
// OUT_MODE: 0 bf16 [m][n], 1 bf16 vT[(b*8+h)*64+d][s], 2 fp32 [m][n]
template <bool A_BF16, int OUT_MODE, int BN>
__device__ __forceinline__ void gemm_body(const void* __restrict__ Ap,
                                          const u16* __restrict__ Bt,
                                          const float* __restrict__ bias,
                                          void* __restrict__ outp, int bidx) {
  constexpr int NF = BN / 32;
  constexpr int NBN = 512 / BN;
  __shared__ __align__(16) u16 As[128][72];
  __shared__ __align__(16) u16 Bs[BN][72];
  int tid = threadIdx.x;
  int lane = tid & 63, wid = tid >> 6;
  int wm = wid >> 1, wn = wid & 1;
  int lr = lane & 15, lg = lane >> 4;
  int bm = bidx / NBN, bn = bidx % NBN;

  f32x4 acc[4][NF];
#pragma unroll
  for (int i = 0; i < 4; ++i)
#pragma unroll
    for (int j = 0; j < NF; ++j) {
      f32x4 z = {0.f, 0.f, 0.f, 0.f};
      acc[i][j] = z;
    }

  for (int kt = 0; kt < 8; ++kt) {
    int k0 = kt * 64;
    if (!A_BF16) {
      const float* A = (const float*)Ap;
#pragma unroll
      for (int i = 0; i < 8; ++i) {
        int idx = i * 256 + tid;
        int row = idx >> 4, c4 = idx & 15;
        float4 v = *(const float4*)(A + (size_t)(bm * 128 + row) * 512 + k0 + c4 * 4);
        ushort4 pk = make_ushort4(f2bf(v.x), f2bf(v.y), f2bf(v.z), f2bf(v.w));
        *(ushort4*)&As[row][c4 * 4] = pk;
      }
    } else {
      const u16* A = (const u16*)Ap;
#pragma unroll
      for (int i = 0; i < 4; ++i) {
        int idx = i * 256 + tid;
        int row = idx >> 3, c8 = idx & 7;
        uint4 v = *(const uint4*)(A + (size_t)(bm * 128 + row) * 512 + k0 + c8 * 8);
        *(uint4*)&As[row][c8 * 8] = v;
      }
    }
#pragma unroll
    for (int i = 0; i < BN / 32; ++i) {
      int idx = i * 256 + tid;
      int row = idx >> 3, c8 = idx & 7;
      uint4 v = *(const uint4*)(Bt + (size_t)(bn * BN + row) * 512 + k0 + c8 * 8);
      *(uint4*)&Bs[row][c8 * 8] = v;
    }
    __syncthreads();
#pragma unroll
    for (int kk = 0; kk < 2; ++kk) {
      bf16x8 af[4], bfr[NF];
#pragma unroll
      for (int mf = 0; mf < 4; ++mf)
        af[mf] = *(const bf16x8*)&As[wm * 64 + mf * 16 + lr][kk * 32 + lg * 8];
#pragma unroll
      for (int nf = 0; nf < NF; ++nf)
        bfr[nf] = *(const bf16x8*)&Bs[wn * (BN / 2) + nf * 16 + lr][kk * 32 + lg * 8];
#pragma unroll
      for (int mf = 0; mf < 4; ++mf)
#pragma unroll
        for (int nf = 0; nf < NF; ++nf)
          acc[mf][nf] = mfma16(af[mf], bfr[nf], acc[mf][nf]);
    }
    __syncthreads();
  }

#pragma unroll
  for (int mf = 0; mf < 4; ++mf) {
#pragma unroll
    for (int nf = 0; nf < NF; ++nf) {
      int m = bm * 128 + wm * 64 + mf * 16 + lg * 4;
      int n = bn * BN + wn * (BN / 2) + nf * 16 + lr;
      float bia = bias[n];
      if (OUT_MODE == 0) {
        u16* o = (u16*)outp;
#pragma unroll
        for (int r = 0; r < 4; ++r)
          o[(size_t)(m + r) * 512 + n] = f2bf(acc[mf][nf][r] + bia);
      } else if (OUT_MODE == 2) {
        float* o = (float*)outp;
#pragma unroll
        for (int r = 0; r < 4; ++r)
          o[(size_t)(m + r) * 512 + n] = acc[mf][nf][r] + bia;
      } else {
        u16* o = (u16*)outp;
        int b = m >> 11, s = m & 2047;
        int h = n >> 6, d = n & 63;
        ushort4 pk = make_ushort4(f2bf(acc[mf][nf][0] + bia), f2bf(acc[mf][nf][1] + bia),
                                  f2bf(acc[mf][nf][2] + bia), f2bf(acc[mf][nf][3] + bia));
        *(ushort4*)&o[(size_t)((b * 8 + h) * 64 + d) * 2048 + s] = pk;
      }
    }
  }
}

// QKV projections in one launch: blockIdx.y selects Q/K/V
__global__ __launch_bounds__(256) void qkv_k(const float* __restrict__ Q,
                                             const float* __restrict__ K,
                                             const float* __restrict__ V,
                                             const u16* __restrict__ Wt,
                                             const float* __restrict__ bq,
                                             const float* __restrict__ bk,
                                             const float* __restrict__ bv,
                                             u16* __restrict__ outbase) {
  int sel = blockIdx.y;
  const float* A = sel == 0 ? Q : sel == 1 ? K : V;
  const float* bia = sel == 0 ? bq : sel == 1 ? bk : bv;
  const u16* Bt = Wt + (size_t)sel * 262144;
  u16* out = outbase + (size_t)sel * 8192 * 512;
  if (sel == 2)
    gemm_body<false, 1, 128>(A, Bt, bia, out, blockIdx.x);
  else
    gemm_body<false, 0, 128>(A, Bt, bia, out, blockIdx.x);
}

__global__ __launch_bounds__(256) void gemm_out_k(const void* __restrict__ Ap,
                                                  const u16* __restrict__ Bt,
                                                  const float* __restrict__ bias,
                                                  void* __restrict__ outp) {
  gemm_body<true, 2, 64>(Ap, Bt, bias, outp, blockIdx.x);
}

// ---- flash attention, cross-tile pipelined ----
__global__ __launch_bounds__(256) void attn_k(const u16* __restrict__ q,
                                              const u16* __restrict__ kmat,
                                              const u16* __restrict__ vT,
                                              u16* __restrict__ z) {
  __shared__ __align__(16) u16 Ks[2][64][64];   // [buf][key][d], swizzled content
  __shared__ __align__(16) u16 Vs[2][64][64];   // [buf][d][key], swizzled content
  const float C = 0.125f * 1.44269504f;         // 1/sqrt(64) * log2(e)
  int tid = threadIdx.x;
  int lane = tid & 63, w = tid >> 6;
  int lr = lane & 15, lg = lane >> 4;
  bool lo4 = ((lane >> 4) & 1) == 0;
  bool lo5 = (lane >> 5) == 0;
  int bh = blockIdx.x >> 5, qt = blockIdx.x & 31;
  int b = bh >> 3, h = bh & 7;
  size_t qrow0 = (size_t)(b * 2048 + qt * 64 + w * 16);

  bf16x8 qf[2];
#pragma unroll
  for (int kf = 0; kf < 2; ++kf)
    qf[kf] = *(const bf16x8*)&q[(qrow0 + lr) * 512 + h * 64 + kf * 32 + lg * 8];

  f32x4 oacc[4];
#pragma unroll
  for (int j = 0; j < 4; ++j) {
    f32x4 zf = {0.f, 0.f, 0.f, 0.f};
    oacc[j] = zf;
  }
  float m = -1e30f, l = 0.f, negmC = 0.f;

  const u16* kbase = kmat + (size_t)(b * 2048) * 512 + h * 64;
  const u16* vbase = vT + (size_t)(bh * 64) * 2048;

  int r0 = tid >> 3;
  int c8s = (tid & 7) ^ (r0 & 7);

  // phase1 (QK^T + softmax + pack): outputs pw_out, sets sc_out (pending
  // oacc rescale factor, to be applied BEFORE the matching PV).
  unsigned pw[4][2];
  float sc_pend = 1.f;
  auto phase1 = [&](int buf, unsigned (*pwo)[2], float& sc_out) {
    f32x4 sacc[4];
#pragma unroll
    for (int j = 0; j < 4; ++j) {
      f32x4 zf = {0.f, 0.f, 0.f, 0.f};
      sacc[j] = zf;
    }
#pragma unroll
    for (int kf = 0; kf < 2; ++kf) {
#pragma unroll
      for (int nf = 0; nf < 4; ++nf) {
        int row = nf * 16 + lr;
        bf16x8 kb = *(const bf16x8*)&Ks[buf][row][(kf * 32 + lg * 8) ^ ((row & 7) << 3)];
        sacc[nf] = mfma16(kb, qf[kf], sacc[nf]);
      }
    }
    float t0 = MX3(sacc[0][0], sacc[0][1], sacc[0][2]);
    float t1 = MX3(sacc[0][3], sacc[1][0], sacc[1][1]);
    float t2 = MX3(sacc[1][2], sacc[1][3], sacc[2][0]);
    float t3 = MX3(sacc[2][1], sacc[2][2], sacc[2][3]);
    float t4 = MX3(sacc[3][0], sacc[3][1], sacc[3][2]);
    float mxl = fmaxf(MX3(t0, t1, t2), MX3(t3, t4, sacc[3][3]));
    sc_out = 1.f;
    if (!__all(mxl - m <= 8.f)) {
      float mx = fmaxf(mxl, __shfl_xor(mxl, 16));
      mx = fmaxf(mx, __shfl_xor(mx, 32));
      float mnew = fmaxf(m, mx);
      float sc = __builtin_amdgcn_exp2f((m - mnew) * C);
      m = mnew;
      negmC = -m * C;
      l *= sc;
      sc_out = sc;
    }
    float rsum = 0.f;
#pragma unroll
    for (int nf = 0; nf < 4; ++nf) {
      float p0 = __builtin_amdgcn_exp2f(fmaf(sacc[nf][0], C, negmC));
      float p1 = __builtin_amdgcn_exp2f(fmaf(sacc[nf][1], C, negmC));
      float p2 = __builtin_amdgcn_exp2f(fmaf(sacc[nf][2], C, negmC));
      float p3 = __builtin_amdgcn_exp2f(fmaf(sacc[nf][3], C, negmC));
      rsum += (p0 + p1) + (p2 + p3);
      pwo[nf][0] = cvtpk(p0, p1);
      pwo[nf][1] = cvtpk(p2, p3);
    }
    rsum += __shfl_xor(rsum, 16);
    rsum += __shfl_xor(rsum, 32);
    l += rsum;
  };

  // phase2: in-register P relayout + PV accumulate (uses pw + vb regs)
  auto phase2 = [&](bf16x8 (*vb)[4]) {
#pragma unroll
    for (int ks = 0; ks < 2; ++ks) {
      unsigned A0 = pw[2 * ks][0], A1 = pw[2 * ks][1];
      unsigned B0 = pw[2 * ks + 1][0], B1 = pw[2 * ks + 1][1];
      unsigned As0 = __shfl_xor(A0, 32), As1 = __shfl_xor(A1, 32);
      unsigned Bs0 = __shfl_xor(B0, 32), Bs1 = __shfl_xor(B1, 32);
      unsigned u0 = lo5 ? A0 : Bs0, u1 = lo5 ? A1 : Bs1;
      unsigned v0 = lo5 ? As0 : B0, v1 = lo5 ? As1 : B1;
      unsigned x0 = __shfl_xor(v0, 16), x1 = __shfl_xor(v1, 16);
      unsigned y0 = __shfl_xor(u0, 16), y1 = __shfl_xor(u1, 16);
      uint4 pv = make_uint4(lo4 ? u0 : x0, lo4 ? u1 : x1,
                            lo4 ? y0 : v0, lo4 ? y1 : v1);
      bf16x8 pa = u4bf(pv);
#pragma unroll
      for (int nfo = 0; nfo < 4; ++nfo)
        oacc[nfo] = mfma16(vb[ks][nfo], pa, oacc[nfo]);
    }
  };

  // apply pending rescale (per-lane skip of *1.0 is exact)
  auto rescale = [&]() {
    if (sc_pend != 1.f) {
#pragma unroll
      for (int nfo = 0; nfo < 4; ++nfo)
#pragma unroll
        for (int r = 0; r < 4; ++r) oacc[nfo][r] *= sc_pend;
    }
  };

  // prologue: K/V(0) -> buf0; then issue K/V(1) -> buf1; phase1(0)
  gl16(&kbase[(size_t)r0 * 512 + c8s * 8],        &Ks[0][0][0] + w * 512);
  gl16(&kbase[(size_t)(r0 + 32) * 512 + c8s * 8], &Ks[0][0][0] + 2048 + w * 512);
  gl16(&vbase[(size_t)r0 * 2048 + c8s * 8],        &Vs[0][0][0] + w * 512);
  gl16(&vbase[(size_t)(r0 + 32) * 2048 + c8s * 8], &Vs[0][0][0] + 2048 + w * 512);
  asm volatile("s_waitcnt vmcnt(0)" ::: "memory");
  __syncthreads();
  {
    u16* KL = &Ks[1][0][0];
    u16* VL = &Vs[1][0][0];
    gl16(&kbase[(size_t)(64 + r0) * 512 + c8s * 8],       KL + w * 512);
    gl16(&kbase[(size_t)(64 + r0 + 32) * 512 + c8s * 8],  KL + 2048 + w * 512);
    gl16(&vbase[(size_t)r0 * 2048 + 64 + c8s * 8],        VL + w * 512);
    gl16(&vbase[(size_t)(r0 + 32) * 2048 + 64 + c8s * 8], VL + 2048 + w * 512);
  }
  phase1(0, pw, sc_pend);   // sc_pend=sc_0 (applied to zero oacc -> no-op)

  for (int t = 0; t < 31; ++t) {
    int cur = t & 1;
    // (A) vb(t) <- Vs[cur] (regs; reads complete before the barrier crossing)
    bf16x8 vb[2][4];
#pragma unroll
    for (int ks = 0; ks < 2; ++ks)
#pragma unroll
      for (int nfo = 0; nfo < 4; ++nfo) {
        int row = nfo * 16 + lr;
        vb[ks][nfo] = *(const bf16x8*)&Vs[cur][row][(ks * 32 + lg * 8) ^ ((row & 7) << 3)];
      }
    // (B) K/V(t+1) landed; all waves done reading tile t LDS
    asm volatile("s_waitcnt vmcnt(0)" ::: "memory");
    __syncthreads();
    // (C) issue K/V(t+2) into the buffer tile t vacated
    if (t + 2 <= 31) {
      u16* KL = &Ks[cur][0][0];
      u16* VL = &Vs[cur][0][0];
      gl16(&kbase[(size_t)((t + 2) * 64 + r0) * 512 + c8s * 8],       KL + w * 512);
      gl16(&kbase[(size_t)((t + 2) * 64 + r0 + 32) * 512 + c8s * 8],  KL + 2048 + w * 512);
      gl16(&vbase[(size_t)r0 * 2048 + (t + 2) * 64 + c8s * 8],        VL + w * 512);
      gl16(&vbase[(size_t)(r0 + 32) * 2048 + (t + 2) * 64 + c8s * 8], VL + 2048 + w * 512);
    }
    // (D) oacc -> m_t frame, THEN phase1(t+1) || phase2(t) (reg-independent)
    rescale();                // uses sc_pend from phase1(t)
    float sc_next;
    unsigned pwn[4][2];
    phase1(cur ^ 1, pwn, sc_next);
    phase2(vb);
    sc_pend = sc_next;
#pragma unroll
    for (int nf = 0; nf < 4; ++nf) {
      pw[nf][0] = pwn[nf][0];
      pw[nf][1] = pwn[nf][1];
    }
  }

  // epilogue: rescale to m_31 frame, then phase2(31) (tile 31 in buf1)
  {
    bf16x8 vb[2][4];
#pragma unroll
    for (int ks = 0; ks < 2; ++ks)
#pragma unroll
      for (int nfo = 0; nfo < 4; ++nfo) {
        int row = nfo * 16 + lr;
        vb[ks][nfo] = *(const bf16x8*)&Vs[1][row][(ks * 32 + lg * 8) ^ ((row & 7) << 3)];
      }
    rescale();
    phase2(vb);
  }

  // normalize + vectorized store: lane owns q = lr, 4 consecutive d per nfo
  float rl = 1.f / l;
#pragma unroll
  for (int nfo = 0; nfo < 4; ++nfo) {
    uint2 ow = make_uint2(cvtpk(oacc[nfo][0] * rl, oacc[nfo][1] * rl),
                          cvtpk(oacc[nfo][2] * rl, oacc[nfo][3] * rl));
    *(uint2*)&z[(qrow0 + lr) * 512 + h * 64 + nfo * 16 + lg * 4] = ow;
  }
}

extern "C" void kernel_launch(void* const* d_in, const int* in_sizes, int n_in,
                              void* d_out, int out_size, void* d_ws, size_t ws_size,
                              hipStream_t stream) {
  const float* Q  = (const float*)d_in[0];
  const float* K  = (const float*)d_in[1];
  const float* V  = (const float*)d_in[2];
  const float* Wq = (const float*)d_in[3];
  const float* bq = (const float*)d_in[4];
  const float* Wk = (const float*)d_in[5];
  const float* bk = (const float*)d_in[6];
  const float* Wv = (const float*)d_in[7];
  const float* bv = (const float*)d_in[8];
  const float* Wo = (const float*)d_in[9];
  const float* bo = (const float*)d_in[10];
  float* out = (float*)d_out;

  u16* ws  = (u16*)d_ws;
  u16* Wt  = ws;                                   // 4 x 512*512 (q,k,v,o)
  u16* qws = Wt + 4 * 262144;                      // 8192*512 each (q,k,vT consecutive)
  u16* vTw = qws + (size_t)2 * 8192 * 512;
  u16* zws = qws + (size_t)3 * 8192 * 512;

  wtrans_k<<<dim3(1024, 4), 256, 0, stream>>>(Wq, Wk, Wv, Wo, Wt);
  qkv_k<<<dim3(256, 3), 256, 0, stream>>>(Q, K, V, Wt, bq, bk, bv, qws);
  attn_k<<<1024, 256, 0, stream>>>(qws, qws + (size_t)8192 * 512, vTw, zws);
  gemm_out_k<<<512, 256, 0, stream>>>(zws, Wt + 3 * 262144, bo, out);
}

// Round 13
// 131.444 us; speedup vs baseline: 1.1833x; 1.1833x over previous
//
#include <hip/hip_runtime.h>

// MHA: B=4, S=2048, D_MODEL=512, H=8, D_HEAD=64
// wtrans (W->Wt bf16) + convert (QKV fp32->bf16) -> qkv GEMMs (m97-style
// gl_lds staging) -> flash attn (r8 structure, best measured) -> out proj GEMM.
// r9-r12 lesson: attn schedule restructures all lost to r8's simple structure;
// GEMMs were the un-mined headroom (reg-staged ~370 TF vs gl_lds ~1.7x, m93->m97).

typedef unsigned short u16;
typedef __bf16 bf16x8 __attribute__((ext_vector_type(8)));
typedef float  f32x4  __attribute__((ext_vector_type(4)));

__device__ __forceinline__ u16 f2bf(float x) {
  unsigned u = __float_as_uint(x);
  u += 0x7fffu + ((u >> 16) & 1u);   // RNE
  return (u16)(u >> 16);
}

__device__ __forceinline__ unsigned cvtpk(float lo, float hi) {
  unsigned r;
  asm("v_cvt_pk_bf16_f32 %0, %1, %2" : "=v"(r) : "v"(lo), "v"(hi));
  return r;
}

__device__ __forceinline__ f32x4 mfma16(bf16x8 a, bf16x8 b, f32x4 c) {
  return __builtin_amdgcn_mfma_f32_16x16x32_bf16(a, b, c, 0, 0, 0);
}

// async 16B/lane global->LDS; lds dest is wave-uniform base (HW adds lane*16)
__device__ __forceinline__ void gl16(const u16* g, u16* l) {
  __builtin_amdgcn_global_load_lds(
      (const __attribute__((address_space(1))) void*)g,
      (__attribute__((address_space(3))) void*)l, 16, 0, 0);
}

// ---- W[k][n] fp32 -> Wt[n][k] bf16, all 4 weights in one launch ----
__global__ __launch_bounds__(256) void wtrans_k(const float* __restrict__ W0,
                                                const float* __restrict__ W1,
                                                const float* __restrict__ W2,
                                                const float* __restrict__ W3,
                                                u16* __restrict__ Wt) {
  int sel = blockIdx.y;
  const float* W = sel == 0 ? W0 : sel == 1 ? W1 : sel == 2 ? W2 : W3;
  int idx = blockIdx.x * 256 + threadIdx.x;
  int k = idx >> 9, n = idx & 511;
  Wt[sel * 262144 + n * 512 + k] = f2bf(W[idx]);
}

// ---- Q/K/V fp32 -> bf16, vectorized (8 elems/thread) ----
__global__ __launch_bounds__(256) void convert_k(const float* __restrict__ X0,
                                                 const float* __restrict__ X1,
                                                 const float* __restrict__ X2,
                                                 u16* __restrict__ O0,
                                                 u16* __restrict__ O1,
                                                 u16* __restrict__ O2) {
  int sel = blockIdx.y;
  const float* X = sel == 0 ? X0 : sel == 1 ? X1 : X2;
  u16* O = sel == 0 ? O0 : sel == 1 ? O1 : O2;
  size_t i = ((size_t)blockIdx.x * 256 + threadIdx.x) * 8;
  float4 a = *(const float4*)(X + i);
  float4 b = *(const float4*)(X + i + 4);
  uint4 pk = make_uint4(cvtpk(a.x, a.y), cvtpk(a.z, a.w),
                        cvtpk(b.x, b.y), cvtpk(b.z, b.w));
  *(uint4*)(O + i) = pk;
}

// ---- m97-style bf16 GEMM: A[8192x512] @ Bt^T + bias (Bt [n][k] bf16) ----
// gl_lds staging, pre-swizzled source + XOR fragment reads (rule #21),
// single-buffered LDS, 2 barriers per BK=64 step.
// OUT_MODE: 0 bf16 [m][n], 1 bf16 vT[(b*8+h)*64+d][s], 2 fp32 [m][n]
template <int OUT_MODE, int BN>
__device__ __forceinline__ void gemm_body(const u16* __restrict__ A,
                                          const u16* __restrict__ Bt,
                                          const float* __restrict__ bias,
                                          void* __restrict__ outp, int bidx) {
  constexpr int NF = BN / 32;
  constexpr int NBN = 512 / BN;
  __shared__ __align__(16) u16 As[128][64];
  __shared__ __align__(16) u16 Bs[BN][64];
  int tid = threadIdx.x;
  int lane = tid & 63, wid = tid >> 6;
  int wm = wid >> 1, wn = wid & 1;
  int lr = lane & 15, lg = lane >> 4;
  int bm = bidx / NBN, bn = bidx % NBN;

  int r0 = tid >> 3;                 // 0..31
  int c8s = (tid & 7) ^ (r0 & 7);    // pre-swizzled source chunk col
  const u16* Ab = A + (size_t)(bm * 128) * 512;
  const u16* Bb = Bt + (size_t)(bn * BN) * 512;

  f32x4 acc[4][NF];
#pragma unroll
  for (int i = 0; i < 4; ++i)
#pragma unroll
    for (int j = 0; j < NF; ++j) {
      f32x4 z = {0.f, 0.f, 0.f, 0.f};
      acc[i][j] = z;
    }

  for (int kt = 0; kt < 8; ++kt) {
    int k0 = kt * 64;
    // stage A (128x64) and B (BNx64) via gl_lds, linear dest, swizzled source
#pragma unroll
    for (int i = 0; i < 4; ++i)
      gl16(&Ab[(size_t)(i * 32 + r0) * 512 + k0 + c8s * 8],
           &As[0][0] + i * 2048 + wid * 512);
#pragma unroll
    for (int i = 0; i < BN / 32; ++i)
      gl16(&Bb[(size_t)(i * 32 + r0) * 512 + k0 + c8s * 8],
           &Bs[0][0] + i * 2048 + wid * 512);
    __syncthreads();   // drains vmcnt+lgkm, tiles visible
#pragma unroll
    for (int kk = 0; kk < 2; ++kk) {
      bf16x8 af[4], bfr[NF];
      int sw = (lr & 7) << 3;        // row&7 == lr&7 for all fragment rows
#pragma unroll
      for (int mf = 0; mf < 4; ++mf)
        af[mf] = *(const bf16x8*)&As[wm * 64 + mf * 16 + lr][(kk * 32 + lg * 8) ^ sw];
#pragma unroll
      for (int nf = 0; nf < NF; ++nf)
        bfr[nf] = *(const bf16x8*)&Bs[wn * (BN / 2) + nf * 16 + lr][(kk * 32 + lg * 8) ^ sw];
#pragma unroll
      for (int mf = 0; mf < 4; ++mf)
#pragma unroll
        for (int nf = 0; nf < NF; ++nf)
          acc[mf][nf] = mfma16(af[mf], bfr[nf], acc[mf][nf]);
    }
    __syncthreads();   // all reads done before next-tile staging
  }

#pragma unroll
  for (int mf = 0; mf < 4; ++mf) {
#pragma unroll
    for (int nf = 0; nf < NF; ++nf) {
      int m = bm * 128 + wm * 64 + mf * 16 + lg * 4;
      int n = bn * BN + wn * (BN / 2) + nf * 16 + lr;
      float bia = bias[n];
      if (OUT_MODE == 0) {
        u16* o = (u16*)outp;
#pragma unroll
        for (int r = 0; r < 4; ++r)
          o[(size_t)(m + r) * 512 + n] = f2bf(acc[mf][nf][r] + bia);
      } else if (OUT_MODE == 2) {
        float* o = (float*)outp;
#pragma unroll
        for (int r = 0; r < 4; ++r)
          o[(size_t)(m + r) * 512 + n] = acc[mf][nf][r] + bia;
      } else {
        u16* o = (u16*)outp;
        int b = m >> 11, s = m & 2047;
        int h = n >> 6, d = n & 63;
        ushort4 pk = make_ushort4(f2bf(acc[mf][nf][0] + bia), f2bf(acc[mf][nf][1] + bia),
                                  f2bf(acc[mf][nf][2] + bia), f2bf(acc[mf][nf][3] + bia));
        *(ushort4*)&o[(size_t)((b * 8 + h) * 64 + d) * 2048 + s] = pk;
      }
    }
  }
}

// QKV projections in one launch: blockIdx.y selects Q/K/V (A pre-converted bf16)
__global__ __launch_bounds__(256) void qkv_k(const u16* __restrict__ Aq,
                                             const u16* __restrict__ Ak,
                                             const u16* __restrict__ Av,
                                             const u16* __restrict__ Wt,
                                             const float* __restrict__ bq,
                                             const float* __restrict__ bk,
                                             const float* __restrict__ bv,
                                             u16* __restrict__ outbase) {
  int sel = blockIdx.y;
  const u16* A = sel == 0 ? Aq : sel == 1 ? Ak : Av;
  const float* bia = sel == 0 ? bq : sel == 1 ? bk : bv;
  const u16* Bt = Wt + (size_t)sel * 262144;
  u16* out = outbase + (size_t)sel * 8192 * 512;
  if (sel == 2)
    gemm_body<1, 128>(A, Bt, bia, out, blockIdx.x);
  else
    gemm_body<0, 128>(A, Bt, bia, out, blockIdx.x);
}

__global__ __launch_bounds__(256) void gemm_out_k(const u16* __restrict__ Ap,
                                                  const u16* __restrict__ Bt,
                                                  const float* __restrict__ bias,
                                                  void* __restrict__ outp) {
  gemm_body<2, 64>(Ap, Bt, bias, outp, blockIdx.x);
}

// ---- flash attention: r8 structure verbatim (best measured: 78 us) ----
// S^T = mfma(K,Q): lane owns q = lane&15, keys nf*16+lg*4+r -> in-register softmax.
// O^T = mfma(V,P): oacc q-index = lane&15 too -> per-lane m/l, no shuffles.
// K/V staging: global_load_lds, K dbuf / V single, counted vmcnt.
__global__ __launch_bounds__(256) void attn_k(const u16* __restrict__ q,
                                              const u16* __restrict__ kmat,
                                              const u16* __restrict__ vT,
                                              u16* __restrict__ z) {
  __shared__ __align__(16) u16 Ks[2][64][64];   // [buf][key][d], swizzled content
  __shared__ __align__(16) u16 Vs[64][64];      // [d][key], swizzled content
  __shared__ __align__(16) u16 Ps[4][16][72];   // per-wave P[q][key]
  const float C = 0.125f * 1.44269504f;         // 1/sqrt(64) * log2(e)
  int tid = threadIdx.x;
  int lane = tid & 63, w = tid >> 6;
  int lr = lane & 15, lg = lane >> 4;
  int bh = blockIdx.x >> 5, qt = blockIdx.x & 31;
  int b = bh >> 3, h = bh & 7;
  size_t qrow0 = (size_t)(b * 2048 + qt * 64 + w * 16);

  bf16x8 qf[2];
#pragma unroll
  for (int kf = 0; kf < 2; ++kf)
    qf[kf] = *(const bf16x8*)&q[(qrow0 + lr) * 512 + h * 64 + kf * 32 + lg * 8];

  f32x4 oacc[4];
#pragma unroll
  for (int j = 0; j < 4; ++j) {
    f32x4 zf = {0.f, 0.f, 0.f, 0.f};
    oacc[j] = zf;
  }
  float m = -1e30f, l = 0.f, negmC = 0.f;

  const u16* kbase = kmat + (size_t)(b * 2048) * 512 + h * 64;
  const u16* vbase = vT + (size_t)(bh * 64) * 2048;

  int r0 = tid >> 3;                         // 0..31
  int c8s = (tid & 7) ^ (r0 & 7);
  // prologue: K(0) -> buf0
  gl16(&kbase[(size_t)r0 * 512 + c8s * 8],        &Ks[0][0][0] + w * 512);
  gl16(&kbase[(size_t)(r0 + 32) * 512 + c8s * 8], &Ks[0][0][0] + 2048 + w * 512);
  __syncthreads();

  for (int kt = 0; kt < 32; ++kt) {
    int cur = kt & 1;
    // issue V(kt) (waited mid-tile via vmcnt), then K(kt+1) (stays in flight)
    gl16(&vbase[(size_t)r0 * 2048 + kt * 64 + c8s * 8],        &Vs[0][0] + w * 512);
    gl16(&vbase[(size_t)(r0 + 32) * 2048 + kt * 64 + c8s * 8], &Vs[0][0] + 2048 + w * 512);
    if (kt < 31) {
      u16* KL = &Ks[cur ^ 1][0][0];
      gl16(&kbase[(size_t)((kt + 1) * 64 + r0) * 512 + c8s * 8],        KL + w * 512);
      gl16(&kbase[(size_t)((kt + 1) * 64 + r0 + 32) * 512 + c8s * 8],  KL + 2048 + w * 512);
    }

    // S^T = K @ Q^T : sacc[nf][r] = S[q=lr][key = nf*16 + lg*4 + r]
    f32x4 sacc[4];
#pragma unroll
    for (int j = 0; j < 4; ++j) {
      f32x4 zf = {0.f, 0.f, 0.f, 0.f};
      sacc[j] = zf;
    }
#pragma unroll
    for (int kf = 0; kf < 2; ++kf) {
#pragma unroll
      for (int nf = 0; nf < 4; ++nf) {
        int row = nf * 16 + lr;
        bf16x8 kb = *(const bf16x8*)&Ks[cur][row][(kf * 32 + lg * 8) ^ ((row & 7) << 3)];
        sacc[nf] = mfma16(kb, qf[kf], sacc[nf]);
      }
    }

    // in-register tile max + 2 shuffles across lg groups
    float mx0 = fmaxf(fmaxf(sacc[0][0], sacc[0][1]), fmaxf(sacc[0][2], sacc[0][3]));
    float mx1 = fmaxf(fmaxf(sacc[1][0], sacc[1][1]), fmaxf(sacc[1][2], sacc[1][3]));
    float mx2 = fmaxf(fmaxf(sacc[2][0], sacc[2][1]), fmaxf(sacc[2][2], sacc[2][3]));
    float mx3 = fmaxf(fmaxf(sacc[3][0], sacc[3][1]), fmaxf(sacc[3][2], sacc[3][3]));
    float mx = fmaxf(fmaxf(mx0, mx1), fmaxf(mx2, mx3));
    mx = fmaxf(mx, __shfl_xor(mx, 16));
    mx = fmaxf(mx, __shfl_xor(mx, 32));

    // defer-max (T13): rescale only when tile max exceeds running max + 8
    if (!__all(mx - m <= 8.f)) {
      float mnew = fmaxf(m, mx);
      float sc = __builtin_amdgcn_exp2f((m - mnew) * C);
      m = mnew;
      negmC = -m * C;
      l *= sc;
#pragma unroll
      for (int nfo = 0; nfo < 4; ++nfo)
#pragma unroll
        for (int r = 0; r < 4; ++r) oacc[nfo][r] *= sc;
    }

    // P = exp2(S*C - m*C), pack to bf16 pairs, store 8B per nf
    float rsum = 0.f;
#pragma unroll
    for (int nf = 0; nf < 4; ++nf) {
      float p0 = __builtin_amdgcn_exp2f(fmaf(sacc[nf][0], C, negmC));
      float p1 = __builtin_amdgcn_exp2f(fmaf(sacc[nf][1], C, negmC));
      float p2 = __builtin_amdgcn_exp2f(fmaf(sacc[nf][2], C, negmC));
      float p3 = __builtin_amdgcn_exp2f(fmaf(sacc[nf][3], C, negmC));
      rsum += (p0 + p1) + (p2 + p3);
      uint2 pw = make_uint2(cvtpk(p0, p1), cvtpk(p2, p3));
      *(uint2*)&Ps[w][lr][nf * 16 + lg * 4] = pw;
    }
    rsum += __shfl_xor(rsum, 16);
    rsum += __shfl_xor(rsum, 32);
    l += rsum;

    // order Ps writes before Ps reads; wait V(kt) landed (counted: K prefetch
    // stays in flight); barrier makes all waves' V chunks visible.
    asm volatile("s_waitcnt lgkmcnt(0)" ::: "memory");
    if (kt < 31) {
      asm volatile("s_waitcnt vmcnt(2)" ::: "memory");
    } else {
      asm volatile("s_waitcnt vmcnt(0)" ::: "memory");
    }
    __builtin_amdgcn_s_barrier();

    // O^T += V^T @ P^T : oacc[nfo][r] = O[q=lr][d = nfo*16 + lg*4 + r]
#pragma unroll
    for (int ks = 0; ks < 2; ++ks) {
      bf16x8 pa = *(const bf16x8*)&Ps[w][lr][ks * 32 + lg * 8];
#pragma unroll
      for (int nfo = 0; nfo < 4; ++nfo) {
        int row = nfo * 16 + lr;
        bf16x8 vbr = *(const bf16x8*)&Vs[row][(ks * 32 + lg * 8) ^ ((row & 7) << 3)];
        oacc[nfo] = mfma16(vbr, pa, oacc[nfo]);
      }
    }
    __syncthreads();
  }

  // normalize + vectorized store: lane owns q = lr, 4 consecutive d per nfo
  float rl = 1.f / l;
#pragma unroll
  for (int nfo = 0; nfo < 4; ++nfo) {
    uint2 pw = make_uint2(cvtpk(oacc[nfo][0] * rl, oacc[nfo][1] * rl),
                          cvtpk(oacc[nfo][2] * rl, oacc[nfo][3] * rl));
    *(uint2*)&z[(qrow0 + lr) * 512 + h * 64 + nfo * 16 + lg * 4] = pw;
  }
}

extern "C" void kernel_launch(void* const* d_in, const int* in_sizes, int n_in,
                              void* d_out, int out_size, void* d_ws, size_t ws_size,
                              hipStream_t stream) {
  const float* Q  = (const float*)d_in[0];
  const float* K  = (const float*)d_in[1];
  const float* V  = (const float*)d_in[2];
  const float* Wq = (const float*)d_in[3];
  const float* bq = (const float*)d_in[4];
  const float* Wk = (const float*)d_in[5];
  const float* bk = (const float*)d_in[6];
  const float* Wv = (const float*)d_in[7];
  const float* bv = (const float*)d_in[8];
  const float* Wo = (const float*)d_in[9];
  const float* bo = (const float*)d_in[10];
  float* out = (float*)d_out;

  u16* ws  = (u16*)d_ws;
  u16* Wt  = ws;                                   // 4 x 512*512 (q,k,v,o)
  u16* qws = Wt + 4 * 262144;                      // 8192*512 each
  u16* kws = qws + (size_t)8192 * 512;
  u16* vTw = kws + (size_t)8192 * 512;             // [(b*8+h)*64+d][2048]
  u16* zws = vTw + (size_t)8192 * 512;

  // bf16 copies of Q/K/V: scratch in regions dead until later stages.
  // AbfQ/AbfK live in d_out (overwritten by gemm_out at the end);
  // AbfV overlaps zws (attn writes zws only after qkv finished reading AbfV).
  u16* AbfQ = (u16*)d_out;                         // 8192*512 u16
  u16* AbfK = AbfQ + (size_t)8192 * 512;           // d_out is 16MB fp32 = fits both
  u16* AbfV = zws;

  wtrans_k<<<dim3(1024, 4), 256, 0, stream>>>(Wq, Wk, Wv, Wo, Wt);
  convert_k<<<dim3(2048, 3), 256, 0, stream>>>(Q, K, V, AbfQ, AbfK, AbfV);
  qkv_k<<<dim3(256, 3), 256, 0, stream>>>(AbfQ, AbfK, AbfV, Wt, bq, bk, bv, qws);
  attn_k<<<1024, 256, 0, stream>>>(qws, kws, vTw, zws);
  gemm_out_k<<<512, 256, 0, stream>>>(zws, Wt + 3 * 262144, bo, out);
}

// Round 14
// 119.084 us; speedup vs baseline: 1.3061x; 1.1038x over previous
//
#include <hip/hip_runtime.h>

// MHA: B=4, S=2048, D_MODEL=512, H=8, D_HEAD=64
// prep (Wt transpose + QKV fp32->bf16, one launch) -> qkv GEMMs (m97-style
// gl_lds, kt fully unrolled) -> flash attn (r8 skeleton + VALU trims) -> out GEMM.
// r14 attn trims vs r8: lane-local defer-max condition (shuffles only in rare
// branch), per-lane partial l (combined once at end), 2x-unrolled tile loop
// with literal K-buffer pointers, max3 reduction tree.

typedef unsigned short u16;
typedef __bf16 bf16x8 __attribute__((ext_vector_type(8)));
typedef float  f32x4  __attribute__((ext_vector_type(4)));

__device__ __forceinline__ u16 f2bf(float x) {
  unsigned u = __float_as_uint(x);
  u += 0x7fffu + ((u >> 16) & 1u);   // RNE
  return (u16)(u >> 16);
}

__device__ __forceinline__ unsigned cvtpk(float lo, float hi) {
  unsigned r;
  asm("v_cvt_pk_bf16_f32 %0, %1, %2" : "=v"(r) : "v"(lo), "v"(hi));
  return r;
}

__device__ __forceinline__ f32x4 mfma16(bf16x8 a, bf16x8 b, f32x4 c) {
  return __builtin_amdgcn_mfma_f32_16x16x32_bf16(a, b, c, 0, 0, 0);
}

// async 16B/lane global->LDS; lds dest is wave-uniform base (HW adds lane*16)
__device__ __forceinline__ void gl16(const u16* g, u16* l) {
  __builtin_amdgcn_global_load_lds(
      (const __attribute__((address_space(1))) void*)g,
      (__attribute__((address_space(3))) void*)l, 16, 0, 0);
}

#define MX3(a, b, c) fmaxf(fmaxf((a), (b)), (c))

// ---- prep: Wt transpose (y=0..3) + Q/K/V fp32->bf16 convert (y=4..6) ----
__global__ __launch_bounds__(256) void prep_k(const float* __restrict__ W0,
                                              const float* __restrict__ W1,
                                              const float* __restrict__ W2,
                                              const float* __restrict__ W3,
                                              u16* __restrict__ Wt,
                                              const float* __restrict__ Q,
                                              const float* __restrict__ K,
                                              const float* __restrict__ V,
                                              u16* __restrict__ Oq,
                                              u16* __restrict__ Ok,
                                              u16* __restrict__ Ov) {
  int y = blockIdx.y;
  if (y < 4) {
    if (blockIdx.x >= 1024) return;
    const float* W = y == 0 ? W0 : y == 1 ? W1 : y == 2 ? W2 : W3;
    int idx = blockIdx.x * 256 + threadIdx.x;
    int k = idx >> 9, n = idx & 511;
    Wt[y * 262144 + n * 512 + k] = f2bf(W[idx]);
  } else {
    int sel = y - 4;
    const float* X = sel == 0 ? Q : sel == 1 ? K : V;
    u16* O = sel == 0 ? Oq : sel == 1 ? Ok : Ov;
    size_t i = ((size_t)blockIdx.x * 256 + threadIdx.x) * 8;
    float4 a = *(const float4*)(X + i);
    float4 b = *(const float4*)(X + i + 4);
    uint4 pk = make_uint4(cvtpk(a.x, a.y), cvtpk(a.z, a.w),
                          cvtpk(b.x, b.y), cvtpk(b.z, b.w));
    *(uint4*)(O + i) = pk;
  }
}

// ---- m97-style bf16 GEMM: A[8192x512] @ Bt^T + bias (Bt [n][k] bf16) ----
// OUT_MODE: 0 bf16 [m][n], 1 bf16 vT[(b*8+h)*64+d][s], 2 fp32 [m][n]
template <int OUT_MODE, int BN>
__device__ __forceinline__ void gemm_body(const u16* __restrict__ A,
                                          const u16* __restrict__ Bt,
                                          const float* __restrict__ bias,
                                          void* __restrict__ outp, int bidx) {
  constexpr int NF = BN / 32;
  constexpr int NBN = 512 / BN;
  __shared__ __align__(16) u16 As[128][64];
  __shared__ __align__(16) u16 Bs[BN][64];
  int tid = threadIdx.x;
  int lane = tid & 63, wid = tid >> 6;
  int wm = wid >> 1, wn = wid & 1;
  int lr = lane & 15, lg = lane >> 4;
  int bm = bidx / NBN, bn = bidx % NBN;

  int r0 = tid >> 3;
  int c8s = (tid & 7) ^ (r0 & 7);
  const u16* Ab = A + (size_t)(bm * 128) * 512;
  const u16* Bb = Bt + (size_t)(bn * BN) * 512;

  f32x4 acc[4][NF];
#pragma unroll
  for (int i = 0; i < 4; ++i)
#pragma unroll
    for (int j = 0; j < NF; ++j) {
      f32x4 z = {0.f, 0.f, 0.f, 0.f};
      acc[i][j] = z;
    }

#pragma unroll
  for (int kt = 0; kt < 8; ++kt) {
    int k0 = kt * 64;
#pragma unroll
    for (int i = 0; i < 4; ++i)
      gl16(&Ab[(size_t)(i * 32 + r0) * 512 + k0 + c8s * 8],
           &As[0][0] + i * 2048 + wid * 512);
#pragma unroll
    for (int i = 0; i < BN / 32; ++i)
      gl16(&Bb[(size_t)(i * 32 + r0) * 512 + k0 + c8s * 8],
           &Bs[0][0] + i * 2048 + wid * 512);
    __syncthreads();
#pragma unroll
    for (int kk = 0; kk < 2; ++kk) {
      bf16x8 af[4], bfr[NF];
      int sw = (lr & 7) << 3;
#pragma unroll
      for (int mf = 0; mf < 4; ++mf)
        af[mf] = *(const bf16x8*)&As[wm * 64 + mf * 16 + lr][(kk * 32 + lg * 8) ^ sw];
#pragma unroll
      for (int nf = 0; nf < NF; ++nf)
        bfr[nf] = *(const bf16x8*)&Bs[wn * (BN / 2) + nf * 16 + lr][(kk * 32 + lg * 8) ^ sw];
#pragma unroll
      for (int mf = 0; mf < 4; ++mf)
#pragma unroll
        for (int nf = 0; nf < NF; ++nf)
          acc[mf][nf] = mfma16(af[mf], bfr[nf], acc[mf][nf]);
    }
    __syncthreads();
  }

#pragma unroll
  for (int mf = 0; mf < 4; ++mf) {
#pragma unroll
    for (int nf = 0; nf < NF; ++nf) {
      int m = bm * 128 + wm * 64 + mf * 16 + lg * 4;
      int n = bn * BN + wn * (BN / 2) + nf * 16 + lr;
      float bia = bias[n];
      if (OUT_MODE == 0) {
        u16* o = (u16*)outp;
#pragma unroll
        for (int r = 0; r < 4; ++r)
          o[(size_t)(m + r) * 512 + n] = f2bf(acc[mf][nf][r] + bia);
      } else if (OUT_MODE == 2) {
        float* o = (float*)outp;
#pragma unroll
        for (int r = 0; r < 4; ++r)
          o[(size_t)(m + r) * 512 + n] = acc[mf][nf][r] + bia;
      } else {
        u16* o = (u16*)outp;
        int b = m >> 11, s = m & 2047;
        int h = n >> 6, d = n & 63;
        ushort4 pk = make_ushort4(f2bf(acc[mf][nf][0] + bia), f2bf(acc[mf][nf][1] + bia),
                                  f2bf(acc[mf][nf][2] + bia), f2bf(acc[mf][nf][3] + bia));
        *(ushort4*)&o[(size_t)((b * 8 + h) * 64 + d) * 2048 + s] = pk;
      }
    }
  }
}

__global__ __launch_bounds__(256) void qkv_k(const u16* __restrict__ Aq,
                                             const u16* __restrict__ Ak,
                                             const u16* __restrict__ Av,
                                             const u16* __restrict__ Wt,
                                             const float* __restrict__ bq,
                                             const float* __restrict__ bk,
                                             const float* __restrict__ bv,
                                             u16* __restrict__ outbase) {
  int sel = blockIdx.y;
  const u16* A = sel == 0 ? Aq : sel == 1 ? Ak : Av;
  const float* bia = sel == 0 ? bq : sel == 1 ? bk : bv;
  const u16* Bt = Wt + (size_t)sel * 262144;
  u16* out = outbase + (size_t)sel * 8192 * 512;
  if (sel == 2)
    gemm_body<1, 128>(A, Bt, bia, out, blockIdx.x);
  else
    gemm_body<0, 128>(A, Bt, bia, out, blockIdx.x);
}

__global__ __launch_bounds__(256) void gemm_out_k(const u16* __restrict__ Ap,
                                                  const u16* __restrict__ Bt,
                                                  const float* __restrict__ bias,
                                                  void* __restrict__ outp) {
  gemm_body<2, 64>(Ap, Bt, bias, outp, blockIdx.x);
}

// ---- flash attention: r8 skeleton + VALU trims ----
__global__ __launch_bounds__(256) void attn_k(const u16* __restrict__ q,
                                              const u16* __restrict__ kmat,
                                              const u16* __restrict__ vT,
                                              u16* __restrict__ z) {
  __shared__ __align__(16) u16 Ks[2][64][64];   // [buf][key][d], swizzled content
  __shared__ __align__(16) u16 Vs[64][64];      // [d][key], swizzled content
  __shared__ __align__(16) u16 Ps[4][16][72];   // per-wave P[q][key]
  const float C = 0.125f * 1.44269504f;         // 1/sqrt(64) * log2(e)
  int tid = threadIdx.x;
  int lane = tid & 63, w = tid >> 6;
  int lr = lane & 15, lg = lane >> 4;
  int bh = blockIdx.x >> 5, qt = blockIdx.x & 31;
  int b = bh >> 3, h = bh & 7;
  size_t qrow0 = (size_t)(b * 2048 + qt * 64 + w * 16);

  bf16x8 qf[2];
#pragma unroll
  for (int kf = 0; kf < 2; ++kf)
    qf[kf] = *(const bf16x8*)&q[(qrow0 + lr) * 512 + h * 64 + kf * 32 + lg * 8];

  f32x4 oacc[4];
#pragma unroll
  for (int j = 0; j < 4; ++j) {
    f32x4 zf = {0.f, 0.f, 0.f, 0.f};
    oacc[j] = zf;
  }
  float m = -1e30f, l_part = 0.f, negmC = 0.f;

  const u16* kbase = kmat + (size_t)(b * 2048) * 512 + h * 64;
  const u16* vbase = vT + (size_t)(bh * 64) * 2048;

  int r0 = tid >> 3;                         // 0..31
  int c8s = (tid & 7) ^ (r0 & 7);
  int sw = (lr & 7) << 3;                    // fragment-read swizzle (row&7 == lr&7)
  // prologue: K(0) -> buf0
  gl16(&kbase[(size_t)r0 * 512 + c8s * 8],        &Ks[0][0][0] + w * 512);
  gl16(&kbase[(size_t)(r0 + 32) * 512 + c8s * 8], &Ks[0][0][0] + 2048 + w * 512);
  __syncthreads();

  // one KV tile; Kc = current K buffer (literal per call site), Kn = next
  auto tile = [&](int kt, const u16* Kc, u16* Kn) {
    // issue V(kt) (waited mid-tile via vmcnt), then K(kt+1) (stays in flight)
    gl16(&vbase[(size_t)r0 * 2048 + kt * 64 + c8s * 8],        &Vs[0][0] + w * 512);
    gl16(&vbase[(size_t)(r0 + 32) * 2048 + kt * 64 + c8s * 8], &Vs[0][0] + 2048 + w * 512);
    if (kt < 31) {
      gl16(&kbase[(size_t)((kt + 1) * 64 + r0) * 512 + c8s * 8],       Kn + w * 512);
      gl16(&kbase[(size_t)((kt + 1) * 64 + r0 + 32) * 512 + c8s * 8],  Kn + 2048 + w * 512);
    }

    // S^T = K @ Q^T : sacc[nf][r] = S[q=lr][key = nf*16 + lg*4 + r]
    f32x4 sacc[4];
#pragma unroll
    for (int j = 0; j < 4; ++j) {
      f32x4 zf = {0.f, 0.f, 0.f, 0.f};
      sacc[j] = zf;
    }
#pragma unroll
    for (int kf = 0; kf < 2; ++kf) {
#pragma unroll
      for (int nf = 0; nf < 4; ++nf) {
        int row = nf * 16 + lr;
        bf16x8 kb = *(const bf16x8*)&Kc[row * 64 + ((kf * 32 + lg * 8) ^ sw)];
        sacc[nf] = mfma16(kb, qf[kf], sacc[nf]);
      }
    }

    // lane-local 16-value max via max3 triples (8 ops)
    float t0 = MX3(sacc[0][0], sacc[0][1], sacc[0][2]);
    float t1 = MX3(sacc[0][3], sacc[1][0], sacc[1][1]);
    float t2 = MX3(sacc[1][2], sacc[1][3], sacc[2][0]);
    float t3 = MX3(sacc[2][1], sacc[2][2], sacc[2][3]);
    float t4 = MX3(sacc[3][0], sacc[3][1], sacc[3][2]);
    float mxl = fmaxf(MX3(t0, t1, t2), MX3(t3, t4, sacc[3][3]));

    // defer-max: lane-local test is exact (__all over local maxes == row test);
    // cross-lane max + rescale only in the rare uniform branch (keeps m synced).
    if (!__all(mxl - m <= 8.f)) {
      float mx = fmaxf(mxl, __shfl_xor(mxl, 16));
      mx = fmaxf(mx, __shfl_xor(mx, 32));
      float mnew = fmaxf(m, mx);
      float sc = __builtin_amdgcn_exp2f((m - mnew) * C);
      m = mnew;
      negmC = -m * C;
      l_part *= sc;                 // per-lane partial; sc row-synced
#pragma unroll
      for (int nfo = 0; nfo < 4; ++nfo)
#pragma unroll
        for (int r = 0; r < 4; ++r) oacc[nfo][r] *= sc;
    }

    // P = exp2(S*C - m*C); per-lane partial sum only (no per-tile shuffles)
    float rsum = 0.f;
#pragma unroll
    for (int nf = 0; nf < 4; ++nf) {
      float p0 = __builtin_amdgcn_exp2f(fmaf(sacc[nf][0], C, negmC));
      float p1 = __builtin_amdgcn_exp2f(fmaf(sacc[nf][1], C, negmC));
      float p2 = __builtin_amdgcn_exp2f(fmaf(sacc[nf][2], C, negmC));
      float p3 = __builtin_amdgcn_exp2f(fmaf(sacc[nf][3], C, negmC));
      rsum += (p0 + p1) + (p2 + p3);
      uint2 pw = make_uint2(cvtpk(p0, p1), cvtpk(p2, p3));
      *(uint2*)&Ps[w][lr][nf * 16 + lg * 4] = pw;
    }
    l_part += rsum;

    // order Ps writes before Ps reads; wait V(kt) landed (K prefetch in flight)
    asm volatile("s_waitcnt lgkmcnt(0)" ::: "memory");
    if (kt < 31) {
      asm volatile("s_waitcnt vmcnt(2)" ::: "memory");
    } else {
      asm volatile("s_waitcnt vmcnt(0)" ::: "memory");
    }
    __builtin_amdgcn_s_barrier();

    // O^T += V^T @ P^T
#pragma unroll
    for (int ks = 0; ks < 2; ++ks) {
      bf16x8 pa = *(const bf16x8*)&Ps[w][lr][ks * 32 + lg * 8];
#pragma unroll
      for (int nfo = 0; nfo < 4; ++nfo) {
        int row = nfo * 16 + lr;
        bf16x8 vbr = *(const bf16x8*)&Vs[row][(ks * 32 + lg * 8) ^ sw];
        oacc[nfo] = mfma16(vbr, pa, oacc[nfo]);
      }
    }
    __syncthreads();
  };

  for (int ko = 0; ko < 32; ko += 2) {
    tile(ko,     &Ks[0][0][0], &Ks[1][0][0]);
    tile(ko + 1, &Ks[1][0][0], &Ks[0][0][0]);
  }

  // combine per-lane l partials once (row = lanes {lr, lr+16, lr+32, lr+48})
  float l = l_part + __shfl_xor(l_part, 16);
  l += __shfl_xor(l, 32);
  float rl = 1.f / l;
#pragma unroll
  for (int nfo = 0; nfo < 4; ++nfo) {
    uint2 pw = make_uint2(cvtpk(oacc[nfo][0] * rl, oacc[nfo][1] * rl),
                          cvtpk(oacc[nfo][2] * rl, oacc[nfo][3] * rl));
    *(uint2*)&z[(qrow0 + lr) * 512 + h * 64 + nfo * 16 + lg * 4] = pw;
  }
}

extern "C" void kernel_launch(void* const* d_in, const int* in_sizes, int n_in,
                              void* d_out, int out_size, void* d_ws, size_t ws_size,
                              hipStream_t stream) {
  const float* Q  = (const float*)d_in[0];
  const float* K  = (const float*)d_in[1];
  const float* V  = (const float*)d_in[2];
  const float* Wq = (const float*)d_in[3];
  const float* bq = (const float*)d_in[4];
  const float* Wk = (const float*)d_in[5];
  const float* bk = (const float*)d_in[6];
  const float* Wv = (const float*)d_in[7];
  const float* bv = (const float*)d_in[8];
  const float* Wo = (const float*)d_in[9];
  const float* bo = (const float*)d_in[10];
  float* out = (float*)d_out;

  u16* ws  = (u16*)d_ws;
  u16* Wt  = ws;                                   // 4 x 512*512 (q,k,v,o)
  u16* qws = Wt + 4 * 262144;                      // 8192*512 each
  u16* kws = qws + (size_t)8192 * 512;
  u16* vTw = kws + (size_t)8192 * 512;             // [(b*8+h)*64+d][2048]
  u16* zws = vTw + (size_t)8192 * 512;

  // bf16 copies of Q/K/V in regions dead until later stages:
  // AbfQ/AbfK in d_out (overwritten only by final gemm_out), AbfV in zws
  // (attn writes zws only after qkv finished reading AbfV).
  u16* AbfQ = (u16*)d_out;
  u16* AbfK = AbfQ + (size_t)8192 * 512;
  u16* AbfV = zws;

  prep_k<<<dim3(2048, 7), 256, 0, stream>>>(Wq, Wk, Wv, Wo, Wt, Q, K, V,
                                            AbfQ, AbfK, AbfV);
  qkv_k<<<dim3(256, 3), 256, 0, stream>>>(AbfQ, AbfK, AbfV, Wt, bq, bk, bv, qws);
  attn_k<<<1024, 256, 0, stream>>>(qws, kws, vTw, zws);
  gemm_out_k<<<512, 256, 0, stream>>>(zws, Wt + 3 * 262144, bo, out);
}